// Round 16
// baseline (821.232 us; speedup 1.0000x reference)
//
#include <hip/hip_runtime.h>
#include <math.h>

#define Bn   32
#define Sn   256
#define En   512
#define Hn   512
#define Wn   512
#define ENCn 1024
#define G4   2048
#define KTOT 1536

// ---------------- workspace layout (float offsets) ----------------
#define OFF_BSUM  0L             // [32][256][512]   4194304
#define OFF_U3    4194304L       // [32][256][512]   4194304
#define OFF_PE    8388608L       // [32][257][512]   4210688  (live during decode)
#define OFF_WXB   12599296L      // [8cb][512k][256c] 1048576
#define OFF_WHB   13647872L      // [8cb][512k][256c] 1048576
#define OFF_W4B   14696448L      // [8cb][128kq][64][4] 262144
#define OFF_GXW   14958592L      // [2][32][1024] u64 pack2 = 131072 floats
#define OFF_GPH   15089664L      // [2][32][1024] u64 pack2 = 131072 floats
#define OFF_SPART 15220736L      // [2][32][8][256] u64 tagged = 262144 floats
#define OFF_STATE 15482880L      // 8192 ints: gflag[b][16] @ 16*b (init 1)
#define OFF_PB    15491072L      // [32][16][512] pe1 partials = 262144 (own region: setup2 runs pe2 || bsum)
// total ~15753216 floats ~= 63 MB

typedef unsigned long long u64t;

__device__ __forceinline__ float aload(const float* p) {
    return __hip_atomic_load(p, __ATOMIC_RELAXED, __HIP_MEMORY_SCOPE_AGENT);
}
__device__ __forceinline__ int aiload(const int* p) {
    return __hip_atomic_load(p, __ATOMIC_RELAXED, __HIP_MEMORY_SCOPE_AGENT);
}
__device__ __forceinline__ void aistore(int* p, int v) {
    __hip_atomic_store(p, v, __ATOMIC_RELAXED, __HIP_MEMORY_SCOPE_AGENT);
}
__device__ __forceinline__ u64t aload64(const u64t* p) {
    return __hip_atomic_load(p, __ATOMIC_RELAXED, __HIP_MEMORY_SCOPE_AGENT);
}
__device__ __forceinline__ void astore64(u64t* p, u64t v) {
    __hip_atomic_store(p, v, __ATOMIC_RELAXED, __HIP_MEMORY_SCOPE_AGENT);
}
__device__ __forceinline__ u64t pack2(float a, float b) {
    return (u64t)__float_as_uint(a) | ((u64t)__float_as_uint(b) << 32);
}
__device__ __forceinline__ u64t packtag(float a, int t) {
    return (u64t)__float_as_uint(a) | ((u64t)(unsigned)t << 32);
}
__device__ __forceinline__ float lo32(u64t v) { return __uint_as_float((unsigned)(v & 0xffffffffu)); }
__device__ __forceinline__ float hi32(u64t v) { return __uint_as_float((unsigned)(v >> 32)); }

// ---------------- setup1: pe1 || weight-repack || init  (5120 blocks) ----------------
__global__ __launch_bounds__(256) void setup1_kernel(
    const int* __restrict__ wid, const float* __restrict__ emb,
    const float* __restrict__ Wx, const float* __restrict__ Wh,
    const float* __restrict__ W4,
    float* __restrict__ pb, float* __restrict__ WxB, float* __restrict__ WhB,
    float* __restrict__ W4B, u64t* __restrict__ gxw64, u64t* __restrict__ gph64,
    u64t* __restrict__ sp64, int* __restrict__ state)
{
    const int blk = blockIdx.x, tid = threadIdx.x;
    __shared__ int wids[16];
    if (blk < 512) {
        // pe1: block partial sums of emb[wid] over 16-step chunks
        const int b = blk >> 4, sb = blk & 15;
        if (tid < 16) wids[tid] = wid[b * Sn + sb * 16 + tid];
        __syncthreads();
        float a0 = 0.f, a1 = 0.f;
        for (int s = 0; s < 16; ++s) {
            const float* r = emb + (long)wids[s] * En;
            a0 += r[tid]; a1 += r[tid + 256];
        }
        pb[((long)b * 16 + sb) * En + tid] = a0;
        pb[((long)b * 16 + sb) * En + tid + 256] = a1;
    } else if (blk < 4608) {
        const int idx = (blk - 512) * 256 + tid;
        if (idx < 1048576) {
            const int c = idx & 255, k = (idx >> 8) & 511, cb = idx >> 17;
            WxB[idx] = Wx[(long)k * G4 + cb * 256 + c];
            WhB[idx] = Wh[(long)k * G4 + cb * 256 + c];
        }
        if (idx < 262144) {
            const int cc = idx & 3, l = (idx >> 2) & 63, kq = (idx >> 8) & 127, cb = idx >> 15;
            const int k = 4 * kq + cc, j = cb * 64 + l;
            W4B[idx] = W4[(long)k * Wn + j];
        }
    } else {
        const int i = (blk - 4608) * 256 + tid;
        if (i < 65536) { gxw64[i] = 0ULL; gph64[i] = 0ULL; }
        if (i < 131072) sp64[i] = 0ULL;
        if (i < 8192) state[i] = (i < 512) ? 1 : 0;   // gflag=1: gates(1)=0 pre-zeroed
    }
}

// ---------------- setup2: pe2 || u3_gemm || bsum_gemm  (2560 blocks) ----------------
__global__ __launch_bounds__(256) void setup2_kernel(
    const int* __restrict__ wid, const float* __restrict__ enc,
    const float* __restrict__ emb, const float* __restrict__ W1,
    const float* __restrict__ W2, const float* __restrict__ W3,
    const float* __restrict__ pb, float* __restrict__ pe,
    float* __restrict__ u3, float* __restrict__ bsum)
{
    const int blk = blockIdx.x, tid = threadIdx.x;
    __shared__ float As[16][68];
    __shared__ float Bs[16][68];
    __shared__ int wids[16];

    if (blk < 512) {
        // pe2: prefix across chunks + in-chunk scan -> pe
        const int b = blk >> 4, sb = blk & 15;
        if (tid < 16) wids[tid] = wid[b * Sn + sb * 16 + tid];
        __syncthreads();
        float a0 = 0.f, a1 = 0.f;
        for (int j = 0; j < sb; ++j) {
            a0 += pb[((long)b * 16 + j) * En + tid];
            a1 += pb[((long)b * 16 + j) * En + tid + 256];
        }
        float* base = pe + (long)b * 257 * En;
        if (sb == 0) { base[tid] = 0.f; base[tid + 256] = 0.f; }
        for (int s = 0; s < 16; ++s) {
            const float* r = emb + (long)wids[s] * En;
            a0 += r[tid]; a1 += r[tid + 256];
            float* o = base + (long)(sb * 16 + s + 1) * En;
            o[tid] = a0; o[tid + 256] = a1;
        }
        return;
    }

    // GEMM: u3 (blk in [512,1536)) or bsum (blk in [1536,2560)); 64x64 tile, 4x4/thread
    const bool isb = (blk >= 1536);
    const int tix  = isb ? (blk - 1536) : (blk - 512);
    const int col0 = (tix & 7) * 64;
    const int row0 = (tix >> 3) * 64;
    const int kmax = isb ? KTOT : 512;
    const int tm0  = (tid & 15) * 4;
    const int tn0  = (tid >> 4) * 4;
    const int la_r = tid >> 2;
    const int la_k = (tid & 3) * 4;
    const int lb_k = tid >> 4;
    const int lb_n = (tid & 15) * 4;

    float acc[4][4];
#pragma unroll
    for (int i = 0; i < 4; i++)
#pragma unroll
        for (int j = 0; j < 4; j++) acc[i][j] = 0.0f;

    for (int k0 = 0; k0 < kmax; k0 += 16) {
        const int gr = row0 + la_r;
        float4 av, bv;
        if (isb) {
            if (k0 < ENCn) {
                av = *(const float4*)&enc[(long)gr * ENCn + k0 + la_k];
                bv = *(const float4*)&W1[(long)(k0 + lb_k) * Wn + col0 + lb_n];
            } else {
                const int wv = wid[gr];
                av = *(const float4*)&emb[(long)wv * En + (k0 - ENCn) + la_k];
                bv = *(const float4*)&W2[(long)(k0 - ENCn + lb_k) * Wn + col0 + lb_n];
            }
        } else {
            const int wv = wid[gr];
            av = *(const float4*)&emb[(long)wv * En + k0 + la_k];
            bv = *(const float4*)&W3[(long)(k0 + lb_k) * Wn + col0 + lb_n];
        }
        As[la_k + 0][la_r] = av.x;
        As[la_k + 1][la_r] = av.y;
        As[la_k + 2][la_r] = av.z;
        As[la_k + 3][la_r] = av.w;
        *(float4*)&Bs[lb_k][lb_n] = bv;
        __syncthreads();
#pragma unroll
        for (int kk = 0; kk < 16; kk++) {
            float4 a = *(const float4*)&As[kk][tm0];
            float4 b = *(const float4*)&Bs[kk][tn0];
            acc[0][0] += a.x * b.x; acc[0][1] += a.x * b.y; acc[0][2] += a.x * b.z; acc[0][3] += a.x * b.w;
            acc[1][0] += a.y * b.x; acc[1][1] += a.y * b.y; acc[1][2] += a.y * b.z; acc[1][3] += a.y * b.w;
            acc[2][0] += a.z * b.x; acc[2][1] += a.z * b.y; acc[2][2] += a.z * b.z; acc[2][3] += a.z * b.w;
            acc[3][0] += a.w * b.x; acc[3][1] += a.w * b.y; acc[3][2] += a.w * b.z; acc[3][3] += a.w * b.w;
        }
        __syncthreads();
    }
    float* outp = isb ? bsum : u3;
#pragma unroll
    for (int i = 0; i < 4; i++) {
        float4 o = make_float4(acc[i][0], acc[i][1], acc[i][2], acc[i][3]);
        *(float4*)&outp[(long)(row0 + tm0 + i) * Wn + col0 + tn0] = o;
    }
}

// ---------------- decode: VERBATIM K787 (R11/R15 passing kernel) ----------------
// WG (b = wg>>3, cb2 = wg&7):
//   A: poll 8 gflag>=t; load u3 slice + gates gx/gph (u64)
//   B: LSTM (redundant full; h,c in LDS)
//   C: u4 (64-col slice, W4 in LDS) -> qv
//   D: scores rows>=bd -> TAGGED u64 spart2
//   F: per-thread poll own row's 8 tags==t; redundant argmax -> local decision
//   TAIL: x=(pe[bd]-pe[ls])/len; gph(t+1)=h@WhB-slice; gxw(t+1)=x@WxB-slice; drain; gflag=t+1
__global__ __launch_bounds__(256) void decode_kernel(
    const float* __restrict__ bias, const float* __restrict__ vt1,
    const float* __restrict__ bsum, const float* __restrict__ u3,
    const float* __restrict__ pe,   const float* __restrict__ WxB,
    const float* __restrict__ WhB,  const float* __restrict__ W4B,
    u64t* __restrict__ gxw64, u64t* __restrict__ gph64,
    u64t* __restrict__ spart2, int* __restrict__ state,
    const float* __restrict__ hn0, float* __restrict__ out)
{
    __shared__ __align__(16) float wlds[32768];    // W4 slice 128 KB
    __shared__ __align__(16) float hld[512];
    __shared__ __align__(16) float cld[512];
    __shared__ __align__(16) float xld[512];
    __shared__ __align__(16) float sgp[4][256];
    __shared__ __align__(16) float sred4[4][64];
    __shared__ float qv[64];
    __shared__ float s_svt[64];
    __shared__ float s_wv[4];
    __shared__ int   s_wi[4];

    const int wg   = blockIdx.x;
    const int tid  = threadIdx.x;
    const int lane = tid & 63;
    const int wv   = tid >> 6;
    const int b    = wg >> 3;
    const int cb2  = wg & 7;

    int* gflag = state;            // [b][16]
    const float4* W4B4 = (const float4*)W4B;
    float4* wlds4 = (float4*)wlds;
    const float4* h4 = (const float4*)hld;
    const float2* pef2 = (const float2*)pe;

    // preload W4 slice, vt slice, h/c init
    {
        const float4* src = W4B4 + (long)cb2 * 8192;
        for (int i = tid; i < 8192; i += 256) wlds4[i] = src[i];
    }
    if (tid < 64) s_svt[tid] = vt1[cb2 * 64 + tid];
    cld[tid]       = hn0[b * Hn + tid];
    cld[256 + tid] = hn0[b * Hn + 256 + tid];
    hld[tid] = 0.f; hld[256 + tid] = 0.f;
    const float2* bias2 = (const float2*)bias;
    const float2 bi  = bias2[tid];
    const float2 bf  = bias2[256 + tid];
    const float2 bg_ = bias2[512 + tid];
    const float2 bo  = bias2[768 + tid];
    __syncthreads();

    int bd = 0, ls = 0;

    for (int t = 1; t <= Sn; ++t) {
        const long cur  = (long)(t & 1) * 32768;     // u64 parity offset for gxw/gph
        const long scur = (long)(t & 1) * 65536;     // u64 parity offset for spart2

        // ---- A: wait for gates(t) ----
        if (tid < 8) {
            const int* g = gflag + 16 * b + tid;
            while (aiload(g) < t) __builtin_amdgcn_s_sleep(1);
        }
        __syncthreads();
        float u3v = 0.f;
        if (tid < 64) u3v = aload(&u3[((long)b * Sn + bd) * Wn + cb2 * 64 + tid]);
        const long gb = cur + (long)b * 1024;
        const u64t gx0 = aload64(&gxw64[gb + tid]);
        const u64t gx1 = aload64(&gxw64[gb + 256 + tid]);
        const u64t gx2 = aload64(&gxw64[gb + 512 + tid]);
        const u64t gx3 = aload64(&gxw64[gb + 768 + tid]);
        const u64t gh0 = aload64(&gph64[gb + tid]);
        const u64t gh1 = aload64(&gph64[gb + 256 + tid]);
        const u64t gh2 = aload64(&gph64[gb + 512 + tid]);
        const u64t gh3 = aload64(&gph64[gb + 768 + tid]);

        // ---- B: LSTM (redundant full) ----
        {
            const int j0 = 2 * tid, j1 = j0 + 1;
            const float igA = lo32(gx0) + lo32(gh0) + bi.x;
            const float igB = hi32(gx0) + hi32(gh0) + bi.y;
            const float fgA = lo32(gx1) + lo32(gh1) + bf.x;
            const float fgB = hi32(gx1) + hi32(gh1) + bf.y;
            const float ggA = lo32(gx2) + lo32(gh2) + bg_.x;
            const float ggB = hi32(gx2) + hi32(gh2) + bg_.y;
            const float ogA = lo32(gx3) + lo32(gh3) + bo.x;
            const float ogB = hi32(gx3) + hi32(gh3) + bo.y;
            const float sfA = 1.f / (1.f + expf(-fgA));
            const float siA = 1.f / (1.f + expf(-igA));
            const float soA = 1.f / (1.f + expf(-ogA));
            const float cnA = sfA * cld[j0] + siA * tanhf(ggA);
            const float h2A = soA * tanhf(cnA);
            const float sfB = 1.f / (1.f + expf(-fgB));
            const float siB = 1.f / (1.f + expf(-igB));
            const float soB = 1.f / (1.f + expf(-ogB));
            const float cnB = sfB * cld[j1] + siB * tanhf(ggB);
            const float h2B = soB * tanhf(cnB);
            cld[j0] = cnA; hld[j0] = h2A;
            cld[j1] = cnB; hld[j1] = h2B;
        }
        __syncthreads();

        // ---- C: u4 slice (64 cols), wave K-split ----
        {
            float acc = 0.f;
            const float4* wr = wlds4 + (wv * 32) * 64 + lane;
#pragma unroll 8
            for (int kq = 0; kq < 32; ++kq) {
                const float4 w = wr[kq * 64];
                const float4 hv = h4[wv * 32 + kq];
                acc += w.x * hv.x + w.y * hv.y + w.z * hv.z + w.w * hv.w;
            }
            sred4[wv][lane] = acc;
        }
        __syncthreads();
        if (tid < 64) qv[tid] = sred4[0][tid] + sred4[1][tid] + sred4[2][tid] + sred4[3][tid] + u3v;
        __syncthreads();

        // ---- D: partial scores -> tagged u64 ----
        if (tid >= bd) {
            const float* row = bsum + ((long)b * Sn + tid) * Wn + cb2 * 64;
            float a = 0.f;
#pragma unroll 8
            for (int i = 0; i < 64; ++i)
                a += tanhf(row[i] + qv[i]) * s_svt[i];
            astore64(&spart2[scur + (long)b * 2048 + cb2 * 256 + tid], packtag(a, t));
        }

        // ---- F: per-thread poll own row; redundant argmax ----
        float v = -3.402823e38f; int vi = Sn;
        if (tid >= bd) {
            const u64t* sp = spart2 + scur + (long)b * 2048 + tid;
            u64t e0, e1, e2, e3, e4, e5, e6, e7;
            for (;;) {
                e0 = aload64(&sp[0]);    e1 = aload64(&sp[256]);
                e2 = aload64(&sp[512]);  e3 = aload64(&sp[768]);
                e4 = aload64(&sp[1024]); e5 = aload64(&sp[1280]);
                e6 = aload64(&sp[1536]); e7 = aload64(&sp[1792]);
                const unsigned tt = (unsigned)t;
                if ((unsigned)(e0 >> 32) == tt && (unsigned)(e1 >> 32) == tt &&
                    (unsigned)(e2 >> 32) == tt && (unsigned)(e3 >> 32) == tt &&
                    (unsigned)(e4 >> 32) == tt && (unsigned)(e5 >> 32) == tt &&
                    (unsigned)(e6 >> 32) == tt && (unsigned)(e7 >> 32) == tt) break;
                __builtin_amdgcn_s_sleep(1);
            }
            v = lo32(e0) + lo32(e1) + lo32(e2) + lo32(e3)
              + lo32(e4) + lo32(e5) + lo32(e6) + lo32(e7);
            vi = tid;
        }
#pragma unroll
        for (int off = 32; off; off >>= 1) {
            const float v2 = __shfl_xor(v, off, 64);
            const int   i2 = __shfl_xor(vi, off, 64);
            if (v2 > v || (v2 == v && i2 < vi)) { v = v2; vi = i2; }
        }
        if (lane == 0) { s_wv[wv] = v; s_wi[wv] = vi; }
        __syncthreads();
        {
            float bv = s_wv[0]; int bi_ = s_wi[0];
#pragma unroll
            for (int k = 1; k < 4; ++k)
                if (s_wv[k] > bv || (s_wv[k] == bv && s_wi[k] < bi_)) { bv = s_wv[k]; bi_ = s_wi[k]; }
            const int nb = (bi_ > bd) ? bi_ : bd + 1;
            if (cb2 == 0 && tid == 0 && nb < Sn) out[nb * Bn + b] = 1.0f;
            ls = bd; bd = nb;
        }
        __syncthreads();
        if (bd >= Sn) break;

        // ---- TAIL: gates for t+1 ----
        const long nxt = (long)((t + 1) & 1) * 32768;
        const float2 pa  = pef2[((long)b * 257 + bd) * 256 + tid];
        const float2 pb_ = pef2[((long)b * 257 + ls) * 256 + tid];
        // E1: gph(t+1) slice (256 cols) from L2-resident WhB
        {
            float4 acc = make_float4(0.f, 0.f, 0.f, 0.f);
            const float* wb = WhB + (long)cb2 * 131072;
            const int k0 = wv * 128;
#pragma unroll 4
            for (int k = k0; k < k0 + 128; ++k) {
                const float hk = hld[k];
                const float4 w = *(const float4*)&wb[(long)k * 256 + lane * 4];
                acc.x += hk * w.x; acc.y += hk * w.y; acc.z += hk * w.z; acc.w += hk * w.w;
            }
            *(float4*)&sgp[wv][lane * 4] = acc;
        }
        // x -> LDS (pe loads have landed by now)
        {
            const float inv = 1.0f / (float)max(bd - ls, 1);
            xld[2 * tid]     = (pa.x - pb_.x) * inv;
            xld[2 * tid + 1] = (pa.y - pb_.y) * inv;
        }
        __syncthreads();
        if (tid < 128) {
            const int c0 = 2 * tid, c1 = c0 + 1;
            const float lo = sgp[0][c0] + sgp[1][c0] + sgp[2][c0] + sgp[3][c0];
            const float hi = sgp[0][c1] + sgp[1][c1] + sgp[2][c1] + sgp[3][c1];
            astore64(&gph64[nxt + (long)b * 1024 + cb2 * 128 + tid], pack2(lo, hi));
        }
        __syncthreads();
        // E2: gxw(t+1) slice from L2-resident WxB
        {
            float4 acc = make_float4(0.f, 0.f, 0.f, 0.f);
            const float* wb = WxB + (long)cb2 * 131072;
            const int k0 = wv * 128;
#pragma unroll 4
            for (int k = k0; k < k0 + 128; ++k) {
                const float xk = xld[k];
                const float4 w = *(const float4*)&wb[(long)k * 256 + lane * 4];
                acc.x += xk * w.x; acc.y += xk * w.y; acc.z += xk * w.z; acc.w += xk * w.w;
            }
            *(float4*)&sgp[wv][lane * 4] = acc;
        }
        __syncthreads();
        if (tid < 128) {
            const int c0 = 2 * tid, c1 = c0 + 1;
            const float lo = sgp[0][c0] + sgp[1][c0] + sgp[2][c0] + sgp[3][c0];
            const float hi = sgp[0][c1] + sgp[1][c1] + sgp[2][c1] + sgp[3][c1];
            astore64(&gxw64[nxt + (long)b * 1024 + cb2 * 128 + tid], pack2(lo, hi));
        }
        __syncthreads();   // drains gph + gxw stores (vmcnt 0)
        if (tid == 0) aistore(&gflag[16 * b + cb2], t + 1);
    }
}

extern "C" void kernel_launch(void* const* d_in, const int* in_sizes, int n_in,
                              void* d_out, int out_size, void* d_ws, size_t ws_size,
                              hipStream_t stream)
{
    const int*   wid  = (const int*)d_in[0];
    const float* enc  = (const float*)d_in[1];
    const float* hn0  = (const float*)d_in[2];
    const float* emb  = (const float*)d_in[3];
    // d_in[4] chunk_emb : unused (uniform score shift, argmax-invariant)
    const float* W1   = (const float*)d_in[5];
    const float* W2   = (const float*)d_in[6];
    const float* W3   = (const float*)d_in[7];
    const float* W4   = (const float*)d_in[8];
    const float* vt1  = (const float*)d_in[9];
    // d_in[10] vt2 : unused
    const float* Wx   = (const float*)d_in[11];
    const float* Wh   = (const float*)d_in[12];
    const float* bias = (const float*)d_in[13];

    float* ws    = (float*)d_ws;
    float* bsum  = ws + OFF_BSUM;
    float* u3    = ws + OFF_U3;
    float* pe    = ws + OFF_PE;
    float* WxB   = ws + OFF_WXB;
    float* WhB   = ws + OFF_WHB;
    float* W4B   = ws + OFF_W4B;
    u64t*  gxw64 = (u64t*)(ws + OFF_GXW);
    u64t*  gph64 = (u64t*)(ws + OFF_GPH);
    u64t*  sp2   = (u64t*)(ws + OFF_SPART);
    int*   state = (int*)(ws + OFF_STATE);
    float* pb    = ws + OFF_PB;
    float* out   = (float*)d_out;

    (void)hipMemsetAsync(d_out, 0, (size_t)Sn * Bn * sizeof(float), stream);
    hipLaunchKernelGGL(setup1_kernel, dim3(5120), dim3(256), 0, stream,
                       wid, emb, Wx, Wh, W4, pb, WxB, WhB, W4B, gxw64, gph64, sp2, state);
    hipLaunchKernelGGL(setup2_kernel, dim3(2560), dim3(256), 0, stream,
                       wid, enc, emb, W1, W2, W3, pb, pe, u3, bsum);

    void* args[] = { (void*)&bias, (void*)&vt1, (void*)&bsum, (void*)&u3, (void*)&pe,
                     (void*)&WxB, (void*)&WhB, (void*)&W4B, (void*)&gxw64, (void*)&gph64,
                     (void*)&sp2, (void*)&state, (void*)&hn0, (void*)&out };
    (void)hipLaunchCooperativeKernel((void*)decode_kernel, dim3(256), dim3(256), args, 0, stream);
}

// Round 17
// 782.577 us; speedup vs baseline: 1.0494x; 1.0494x over previous
//
#include <hip/hip_runtime.h>
#include <math.h>

#define Bn   32
#define Sn   256
#define En   512
#define Hn   512
#define Wn   512
#define ENCn 1024
#define G4   2048
#define KTOT 1536

// ---------------- workspace layout (float offsets) ----------------
#define OFF_BSUM  0L             // [32][256][512]   4194304  (pb overlays before bsum_gemm)
#define OFF_U3    4194304L       // [32][256][512]   4194304
#define OFF_PE    8388608L       // [32][257][512]   4210688  (live during decode)
#define OFF_WXB   12599296L      // [8cb][512k][256c] 1048576
#define OFF_WHB   13647872L      // [8cb][512k][256c] 1048576
#define OFF_W4B   14696448L      // [8cb][128kq][64][4] 262144
#define OFF_GXW   14958592L      // [2][32][1024] u64 pack2 = 131072 floats
#define OFF_GPH   15089664L      // [2][32][1024] u64 pack2 = 131072 floats
#define OFF_SPART 15220736L      // [2][32][8][256] u64 tagged = 262144 floats
#define OFF_STATE 15482880L      // 8192 ints: gflag[b][16] @ 16*b (init 1)
// total ~15491072 floats ~= 62 MB

typedef unsigned long long u64t;

__device__ __forceinline__ float aload(const float* p) {
    return __hip_atomic_load(p, __ATOMIC_RELAXED, __HIP_MEMORY_SCOPE_AGENT);
}
__device__ __forceinline__ int aiload(const int* p) {
    return __hip_atomic_load(p, __ATOMIC_RELAXED, __HIP_MEMORY_SCOPE_AGENT);
}
__device__ __forceinline__ void aistore(int* p, int v) {
    __hip_atomic_store(p, v, __ATOMIC_RELAXED, __HIP_MEMORY_SCOPE_AGENT);
}
__device__ __forceinline__ u64t aload64(const u64t* p) {
    return __hip_atomic_load(p, __ATOMIC_RELAXED, __HIP_MEMORY_SCOPE_AGENT);
}
__device__ __forceinline__ void astore64(u64t* p, u64t v) {
    __hip_atomic_store(p, v, __ATOMIC_RELAXED, __HIP_MEMORY_SCOPE_AGENT);
}
__device__ __forceinline__ u64t pack2(float a, float b) {
    return (u64t)__float_as_uint(a) | ((u64t)__float_as_uint(b) << 32);
}
__device__ __forceinline__ u64t packtag(float a, int t) {
    return (u64t)__float_as_uint(a) | ((u64t)(unsigned)t << 32);
}
__device__ __forceinline__ float lo32(u64t v) { return __uint_as_float((unsigned)(v & 0xffffffffu)); }
__device__ __forceinline__ float hi32(u64t v) { return __uint_as_float((unsigned)(v >> 32)); }

// ---------------- init (every launch: graph-replay determinism) ----------------
__global__ void init_kernel(u64t* __restrict__ gxw64, u64t* __restrict__ gph64,
                            u64t* __restrict__ sp64, int* __restrict__ state)
{
    int i = blockIdx.x * blockDim.x + threadIdx.x;
    if (i < 65536) { gxw64[i] = 0ULL; gph64[i] = 0ULL; }
    if (i < 131072) sp64[i] = 0ULL;
    if (i < 8192) state[i] = (i < 512) ? 1 : 0;   // gflag=1: gates(1)=0 pre-zeroed
}

// ---------------- weight repack: WxB/WhB [8][512][256], W4B [8][128][64][4] ----------------
__global__ void wtrans_kernel(const float* __restrict__ Wx, const float* __restrict__ Wh,
                              const float* __restrict__ W4, float* __restrict__ WxB,
                              float* __restrict__ WhB, float* __restrict__ W4B)
{
    int idx = blockIdx.x * 256 + threadIdx.x;
    if (idx < 1048576) {
        const int c = idx & 255, k = (idx >> 8) & 511, cb = idx >> 17;
        WxB[idx] = Wx[(long)k * G4 + cb * 256 + c];
        WhB[idx] = Wh[(long)k * G4 + cb * 256 + c];
    }
    if (idx < 262144) {
        const int cc = idx & 3, l = (idx >> 2) & 63, kq = (idx >> 8) & 127, cb = idx >> 15;
        const int k = 4 * kq + cc, j = cb * 64 + l;
        W4B[idx] = W4[(long)k * Wn + j];
    }
}

// ---------------- pe: parallel prefix sums of inp over s ----------------
__global__ void pe1_kernel(const int* __restrict__ wid, const float* __restrict__ emb,
                           float* __restrict__ pb)
{
    const int b = blockIdx.x, blk = blockIdx.y;
    __shared__ int wids[16];
    if (threadIdx.x < 16) wids[threadIdx.x] = wid[b * Sn + blk * 16 + threadIdx.x];
    __syncthreads();
    float a0 = 0.f, a1 = 0.f;
    for (int s = 0; s < 16; ++s) {
        const float* r = emb + (long)wids[s] * En;
        a0 += r[threadIdx.x]; a1 += r[threadIdx.x + 256];
    }
    pb[((long)b * 16 + blk) * En + threadIdx.x] = a0;
    pb[((long)b * 16 + blk) * En + threadIdx.x + 256] = a1;
}

__global__ void pe2_kernel(const int* __restrict__ wid, const float* __restrict__ emb,
                           const float* __restrict__ pb, float* __restrict__ pe)
{
    const int b = blockIdx.x, blk = blockIdx.y;
    __shared__ int wids[16];
    if (threadIdx.x < 16) wids[threadIdx.x] = wid[b * Sn + blk * 16 + threadIdx.x];
    __syncthreads();
    float a0 = 0.f, a1 = 0.f;
    for (int j = 0; j < blk; ++j) {
        a0 += pb[((long)b * 16 + j) * En + threadIdx.x];
        a1 += pb[((long)b * 16 + j) * En + threadIdx.x + 256];
    }
    float* base = pe + (long)b * 257 * En;
    if (blk == 0) { base[threadIdx.x] = 0.f; base[threadIdx.x + 256] = 0.f; }
    for (int s = 0; s < 16; ++s) {
        const float* r = emb + (long)wids[s] * En;
        a0 += r[threadIdx.x]; a1 += r[threadIdx.x + 256];
        float* o = base + (long)(blk * 16 + s + 1) * En;
        o[threadIdx.x] = a0; o[threadIdx.x + 256] = a1;
    }
}

// ---------------- bsum = enc@W1 + emb[wid]@W2 ----------------
__global__ __launch_bounds__(256) void bsum_gemm(
    const float* __restrict__ enc, const int* __restrict__ wid,
    const float* __restrict__ emb, const float* __restrict__ W1,
    const float* __restrict__ W2, float* __restrict__ bsum)
{
    __shared__ float As[16][68];
    __shared__ float Bs[16][68];
    const int tid  = threadIdx.x;
    const int row0 = blockIdx.y * 64;
    const int col0 = blockIdx.x * 64;
    const int tm0  = (tid & 15) * 4;
    const int tn0  = (tid >> 4) * 4;
    const int la_r = tid >> 2;
    const int la_k = (tid & 3) * 4;
    const int lb_k = tid >> 4;
    const int lb_n = (tid & 15) * 4;

    float acc[4][4];
#pragma unroll
    for (int i = 0; i < 4; i++)
#pragma unroll
        for (int j = 0; j < 4; j++) acc[i][j] = 0.0f;

    for (int k0 = 0; k0 < KTOT; k0 += 16) {
        const int gr = row0 + la_r;
        float4 av;
        if (k0 < ENCn) {
            av = *(const float4*)&enc[(long)gr * ENCn + k0 + la_k];
        } else {
            const int wv = wid[gr];
            av = *(const float4*)&emb[(long)wv * En + (k0 - ENCn) + la_k];
        }
        As[la_k + 0][la_r] = av.x;
        As[la_k + 1][la_r] = av.y;
        As[la_k + 2][la_r] = av.z;
        As[la_k + 3][la_r] = av.w;
        float4 bv;
        if (k0 < ENCn) bv = *(const float4*)&W1[(long)(k0 + lb_k) * Wn + col0 + lb_n];
        else           bv = *(const float4*)&W2[(long)(k0 - ENCn + lb_k) * Wn + col0 + lb_n];
        *(float4*)&Bs[lb_k][lb_n] = bv;
        __syncthreads();
#pragma unroll
        for (int kk = 0; kk < 16; kk++) {
            float4 a = *(const float4*)&As[kk][tm0];
            float4 b = *(const float4*)&Bs[kk][tn0];
            acc[0][0] += a.x * b.x; acc[0][1] += a.x * b.y; acc[0][2] += a.x * b.z; acc[0][3] += a.x * b.w;
            acc[1][0] += a.y * b.x; acc[1][1] += a.y * b.y; acc[1][2] += a.y * b.z; acc[1][3] += a.y * b.w;
            acc[2][0] += a.z * b.x; acc[2][1] += a.z * b.y; acc[2][2] += a.z * b.z; acc[2][3] += a.z * b.w;
            acc[3][0] += a.w * b.x; acc[3][1] += a.w * b.y; acc[3][2] += a.w * b.z; acc[3][3] += a.w * b.w;
        }
        __syncthreads();
    }
#pragma unroll
    for (int i = 0; i < 4; i++) {
        float4 o = make_float4(acc[i][0], acc[i][1], acc[i][2], acc[i][3]);
        *(float4*)&bsum[(long)(row0 + tm0 + i) * Wn + col0 + tn0] = o;
    }
}

// ---------------- u3 = emb[wid]@W3 ----------------
__global__ __launch_bounds__(256) void u3_gemm(
    const int* __restrict__ wid, const float* __restrict__ emb,
    const float* __restrict__ W3, float* __restrict__ u3)
{
    __shared__ float As[16][68];
    __shared__ float Bs[16][68];
    const int tid  = threadIdx.x;
    const int row0 = blockIdx.y * 64;
    const int col0 = blockIdx.x * 64;
    const int tm0  = (tid & 15) * 4;
    const int tn0  = (tid >> 4) * 4;
    const int la_r = tid >> 2;
    const int la_k = (tid & 3) * 4;
    const int lb_k = tid >> 4;
    const int lb_n = (tid & 15) * 4;

    float acc[4][4];
#pragma unroll
    for (int i = 0; i < 4; i++)
#pragma unroll
        for (int j = 0; j < 4; j++) acc[i][j] = 0.0f;

    for (int k0 = 0; k0 < 512; k0 += 16) {
        const int gr = row0 + la_r;
        const int wv = wid[gr];
        float4 av = *(const float4*)&emb[(long)wv * En + k0 + la_k];
        As[la_k + 0][la_r] = av.x;
        As[la_k + 1][la_r] = av.y;
        As[la_k + 2][la_r] = av.z;
        As[la_k + 3][la_r] = av.w;
        *(float4*)&Bs[lb_k][lb_n] = *(const float4*)&W3[(long)(k0 + lb_k) * Wn + col0 + lb_n];
        __syncthreads();
#pragma unroll
        for (int kk = 0; kk < 16; kk++) {
            float4 a = *(const float4*)&As[kk][tm0];
            float4 b = *(const float4*)&Bs[kk][tn0];
            acc[0][0] += a.x * b.x; acc[0][1] += a.x * b.y; acc[0][2] += a.x * b.z; acc[0][3] += a.x * b.w;
            acc[1][0] += a.y * b.x; acc[1][1] += a.y * b.y; acc[1][2] += a.y * b.z; acc[1][3] += a.y * b.w;
            acc[2][0] += a.z * b.x; acc[2][1] += a.z * b.y; acc[2][2] += a.z * b.z; acc[2][3] += a.z * b.w;
            acc[3][0] += a.w * b.x; acc[3][1] += a.w * b.y; acc[3][2] += a.w * b.z; acc[3][3] += a.w * b.w;
        }
        __syncthreads();
    }
#pragma unroll
    for (int i = 0; i < 4; i++) {
        float4 o = make_float4(acc[i][0], acc[i][1], acc[i][2], acc[i][3]);
        *(float4*)&u3[(long)(row0 + tm0 + i) * Wn + col0 + tn0] = o;
    }
}

// ---------------- decode: 32 batches x 8 WGs, batch-local; gates GEMVs in step tail ----------------
// WG (b = wg>>3, cb2 = wg&7):
//   A: poll 8 gflag>=t; load u3 slice + gates gx/gph (u64)
//   B: LSTM (redundant full; h,c in LDS)
//   C: u4 (64-col slice, W4 in LDS) -> qv
//   D: scores rows>=bd -> TAGGED u64 spart2 (tag travels with data: no drain, no flag)
//   F: per-thread poll own row's 8 tags==t; redundant argmax -> local decision
//   TAIL: x=(pe[bd]-pe[ls])/len; gph(t+1)=h@WhB-slice; gxw(t+1)=x@WxB-slice; drain; gflag=t+1
__global__ __launch_bounds__(256) void decode_kernel(
    const float* __restrict__ bias, const float* __restrict__ vt1,
    const float* __restrict__ bsum, const float* __restrict__ u3,
    const float* __restrict__ pe,   const float* __restrict__ WxB,
    const float* __restrict__ WhB,  const float* __restrict__ W4B,
    u64t* __restrict__ gxw64, u64t* __restrict__ gph64,
    u64t* __restrict__ spart2, int* __restrict__ state,
    const float* __restrict__ hn0, float* __restrict__ out)
{
    __shared__ __align__(16) float wlds[32768];    // W4 slice 128 KB
    __shared__ __align__(16) float hld[512];
    __shared__ __align__(16) float cld[512];
    __shared__ __align__(16) float xld[512];
    __shared__ __align__(16) float sgp[4][256];
    __shared__ __align__(16) float sred4[4][64];
    __shared__ float qv[64];
    __shared__ float s_svt[64];
    __shared__ float s_wv[4];
    __shared__ int   s_wi[4];

    const int wg   = blockIdx.x;
    const int tid  = threadIdx.x;
    const int lane = tid & 63;
    const int wv   = tid >> 6;
    const int b    = wg >> 3;
    const int cb2  = wg & 7;

    int* gflag = state;            // [b][16]
    const float4* W4B4 = (const float4*)W4B;
    float4* wlds4 = (float4*)wlds;
    const float4* h4 = (const float4*)hld;
    const float2* pef2 = (const float2*)pe;

    // preload W4 slice, vt slice, h/c init
    {
        const float4* src = W4B4 + (long)cb2 * 8192;
        for (int i = tid; i < 8192; i += 256) wlds4[i] = src[i];
    }
    if (tid < 64) s_svt[tid] = vt1[cb2 * 64 + tid];
    cld[tid]       = hn0[b * Hn + tid];
    cld[256 + tid] = hn0[b * Hn + 256 + tid];
    hld[tid] = 0.f; hld[256 + tid] = 0.f;
    const float2* bias2 = (const float2*)bias;
    const float2 bi  = bias2[tid];
    const float2 bf  = bias2[256 + tid];
    const float2 bg_ = bias2[512 + tid];
    const float2 bo  = bias2[768 + tid];
    __syncthreads();

    int bd = 0, ls = 0;

    for (int t = 1; t <= Sn; ++t) {
        const long cur  = (long)(t & 1) * 32768;     // u64 parity offset for gxw/gph
        const long scur = (long)(t & 1) * 65536;     // u64 parity offset for spart2

        // ---- A: wait for gates(t) ----
        if (tid < 8) {
            const int* g = gflag + 16 * b + tid;
            while (aiload(g) < t) __builtin_amdgcn_s_sleep(1);
        }
        __syncthreads();
        float u3v = 0.f;
        if (tid < 64) u3v = aload(&u3[((long)b * Sn + bd) * Wn + cb2 * 64 + tid]);
        const long gb = cur + (long)b * 1024;
        const u64t gx0 = aload64(&gxw64[gb + tid]);
        const u64t gx1 = aload64(&gxw64[gb + 256 + tid]);
        const u64t gx2 = aload64(&gxw64[gb + 512 + tid]);
        const u64t gx3 = aload64(&gxw64[gb + 768 + tid]);
        const u64t gh0 = aload64(&gph64[gb + tid]);
        const u64t gh1 = aload64(&gph64[gb + 256 + tid]);
        const u64t gh2 = aload64(&gph64[gb + 512 + tid]);
        const u64t gh3 = aload64(&gph64[gb + 768 + tid]);

        // ---- B: LSTM (redundant full) ----
        {
            const int j0 = 2 * tid, j1 = j0 + 1;
            const float igA = lo32(gx0) + lo32(gh0) + bi.x;
            const float igB = hi32(gx0) + hi32(gh0) + bi.y;
            const float fgA = lo32(gx1) + lo32(gh1) + bf.x;
            const float fgB = hi32(gx1) + hi32(gh1) + bf.y;
            const float ggA = lo32(gx2) + lo32(gh2) + bg_.x;
            const float ggB = hi32(gx2) + hi32(gh2) + bg_.y;
            const float ogA = lo32(gx3) + lo32(gh3) + bo.x;
            const float ogB = hi32(gx3) + hi32(gh3) + bo.y;
            const float sfA = 1.f / (1.f + expf(-fgA));
            const float siA = 1.f / (1.f + expf(-igA));
            const float soA = 1.f / (1.f + expf(-ogA));
            const float cnA = sfA * cld[j0] + siA * tanhf(ggA);
            const float h2A = soA * tanhf(cnA);
            const float sfB = 1.f / (1.f + expf(-fgB));
            const float siB = 1.f / (1.f + expf(-igB));
            const float soB = 1.f / (1.f + expf(-ogB));
            const float cnB = sfB * cld[j1] + siB * tanhf(ggB);
            const float h2B = soB * tanhf(cnB);
            cld[j0] = cnA; hld[j0] = h2A;
            cld[j1] = cnB; hld[j1] = h2B;
        }
        __syncthreads();

        // ---- C: u4 slice (64 cols), wave K-split ----
        {
            float acc = 0.f;
            const float4* wr = wlds4 + (wv * 32) * 64 + lane;
#pragma unroll 8
            for (int kq = 0; kq < 32; ++kq) {
                const float4 w = wr[kq * 64];
                const float4 hv = h4[wv * 32 + kq];
                acc += w.x * hv.x + w.y * hv.y + w.z * hv.z + w.w * hv.w;
            }
            sred4[wv][lane] = acc;
        }
        __syncthreads();
        if (tid < 64) qv[tid] = sred4[0][tid] + sred4[1][tid] + sred4[2][tid] + sred4[3][tid] + u3v;
        __syncthreads();

        // ---- D: partial scores -> tagged u64 (no drain/flag needed) ----
        if (tid >= bd) {
            const float* row = bsum + ((long)b * Sn + tid) * Wn + cb2 * 64;
            float a = 0.f;
#pragma unroll 8
            for (int i = 0; i < 64; ++i)
                a += tanhf(row[i] + qv[i]) * s_svt[i];
            astore64(&spart2[scur + (long)b * 2048 + cb2 * 256 + tid], packtag(a, t));
        }

        // ---- F: per-thread poll own row; redundant argmax ----
        float v = -3.402823e38f; int vi = Sn;
        if (tid >= bd) {
            const u64t* sp = spart2 + scur + (long)b * 2048 + tid;
            u64t e0, e1, e2, e3, e4, e5, e6, e7;
            for (;;) {
                e0 = aload64(&sp[0]);    e1 = aload64(&sp[256]);
                e2 = aload64(&sp[512]);  e3 = aload64(&sp[768]);
                e4 = aload64(&sp[1024]); e5 = aload64(&sp[1280]);
                e6 = aload64(&sp[1536]); e7 = aload64(&sp[1792]);
                const unsigned tt = (unsigned)t;
                if ((unsigned)(e0 >> 32) == tt && (unsigned)(e1 >> 32) == tt &&
                    (unsigned)(e2 >> 32) == tt && (unsigned)(e3 >> 32) == tt &&
                    (unsigned)(e4 >> 32) == tt && (unsigned)(e5 >> 32) == tt &&
                    (unsigned)(e6 >> 32) == tt && (unsigned)(e7 >> 32) == tt) break;
                __builtin_amdgcn_s_sleep(1);
            }
            v = lo32(e0) + lo32(e1) + lo32(e2) + lo32(e3)
              + lo32(e4) + lo32(e5) + lo32(e6) + lo32(e7);
            vi = tid;
        }
#pragma unroll
        for (int off = 32; off; off >>= 1) {
            const float v2 = __shfl_xor(v, off, 64);
            const int   i2 = __shfl_xor(vi, off, 64);
            if (v2 > v || (v2 == v && i2 < vi)) { v = v2; vi = i2; }
        }
        if (lane == 0) { s_wv[wv] = v; s_wi[wv] = vi; }
        __syncthreads();
        {
            float bv = s_wv[0]; int bi_ = s_wi[0];
#pragma unroll
            for (int k = 1; k < 4; ++k)
                if (s_wv[k] > bv || (s_wv[k] == bv && s_wi[k] < bi_)) { bv = s_wv[k]; bi_ = s_wi[k]; }
            const int nb = (bi_ > bd) ? bi_ : bd + 1;
            if (cb2 == 0 && tid == 0 && nb < Sn) out[nb * Bn + b] = 1.0f;
            ls = bd; bd = nb;
        }
        __syncthreads();
        if (bd >= Sn) break;

        // ---- TAIL: gates for t+1 ----
        const long nxt = (long)((t + 1) & 1) * 32768;
        // issue pe row loads (x = (pe[bd]-pe[ls])*inv)
        const float2 pa  = pef2[((long)b * 257 + bd) * 256 + tid];
        const float2 pb_ = pef2[((long)b * 257 + ls) * 256 + tid];
        // E1: gph(t+1) slice (256 cols) from L2-resident WhB
        {
            float4 acc = make_float4(0.f, 0.f, 0.f, 0.f);
            const float* wb = WhB + (long)cb2 * 131072;
            const int k0 = wv * 128;
#pragma unroll 4
            for (int k = k0; k < k0 + 128; ++k) {
                const float hk = hld[k];
                const float4 w = *(const float4*)&wb[(long)k * 256 + lane * 4];
                acc.x += hk * w.x; acc.y += hk * w.y; acc.z += hk * w.z; acc.w += hk * w.w;
            }
            *(float4*)&sgp[wv][lane * 4] = acc;
        }
        // x -> LDS (pe loads have landed by now)
        {
            const float inv = 1.0f / (float)max(bd - ls, 1);
            xld[2 * tid]     = (pa.x - pb_.x) * inv;
            xld[2 * tid + 1] = (pa.y - pb_.y) * inv;
        }
        __syncthreads();
        if (tid < 128) {
            const int c0 = 2 * tid, c1 = c0 + 1;
            const float lo = sgp[0][c0] + sgp[1][c0] + sgp[2][c0] + sgp[3][c0];
            const float hi = sgp[0][c1] + sgp[1][c1] + sgp[2][c1] + sgp[3][c1];
            astore64(&gph64[nxt + (long)b * 1024 + cb2 * 128 + tid], pack2(lo, hi));
        }
        __syncthreads();
        // E2: gxw(t+1) slice from L2-resident WxB
        {
            float4 acc = make_float4(0.f, 0.f, 0.f, 0.f);
            const float* wb = WxB + (long)cb2 * 131072;
            const int k0 = wv * 128;
#pragma unroll 4
            for (int k = k0; k < k0 + 128; ++k) {
                const float xk = xld[k];
                const float4 w = *(const float4*)&wb[(long)k * 256 + lane * 4];
                acc.x += xk * w.x; acc.y += xk * w.y; acc.z += xk * w.z; acc.w += xk * w.w;
            }
            *(float4*)&sgp[wv][lane * 4] = acc;
        }
        __syncthreads();
        if (tid < 128) {
            const int c0 = 2 * tid, c1 = c0 + 1;
            const float lo = sgp[0][c0] + sgp[1][c0] + sgp[2][c0] + sgp[3][c0];
            const float hi = sgp[0][c1] + sgp[1][c1] + sgp[2][c1] + sgp[3][c1];
            astore64(&gxw64[nxt + (long)b * 1024 + cb2 * 128 + tid], pack2(lo, hi));
        }
        __syncthreads();   // drains gph + gxw stores (vmcnt 0)
        if (tid == 0) aistore(&gflag[16 * b + cb2], t + 1);
    }
}

extern "C" void kernel_launch(void* const* d_in, const int* in_sizes, int n_in,
                              void* d_out, int out_size, void* d_ws, size_t ws_size,
                              hipStream_t stream)
{
    const int*   wid  = (const int*)d_in[0];
    const float* enc  = (const float*)d_in[1];
    const float* hn0  = (const float*)d_in[2];
    const float* emb  = (const float*)d_in[3];
    // d_in[4] chunk_emb : unused (uniform score shift, argmax-invariant)
    const float* W1   = (const float*)d_in[5];
    const float* W2   = (const float*)d_in[6];
    const float* W3   = (const float*)d_in[7];
    const float* W4   = (const float*)d_in[8];
    const float* vt1  = (const float*)d_in[9];
    // d_in[10] vt2 : unused
    const float* Wx   = (const float*)d_in[11];
    const float* Wh   = (const float*)d_in[12];
    const float* bias = (const float*)d_in[13];

    float* ws    = (float*)d_ws;
    float* bsum  = ws + OFF_BSUM;
    float* u3    = ws + OFF_U3;
    float* pe    = ws + OFF_PE;
    float* WxB   = ws + OFF_WXB;
    float* WhB   = ws + OFF_WHB;
    float* W4B   = ws + OFF_W4B;
    u64t*  gxw64 = (u64t*)(ws + OFF_GXW);
    u64t*  gph64 = (u64t*)(ws + OFF_GPH);
    u64t*  sp2   = (u64t*)(ws + OFF_SPART);
    int*   state = (int*)(ws + OFF_STATE);
    float* out   = (float*)d_out;
    float* pb    = ws + OFF_BSUM;   // pe1 partials overlay bsum (bsum_gemm runs after pe2)

    (void)hipMemsetAsync(d_out, 0, (size_t)Sn * Bn * sizeof(float), stream);
    hipLaunchKernelGGL(init_kernel, dim3(512), dim3(256), 0, stream, gxw64, gph64, sp2, state);
    hipLaunchKernelGGL(wtrans_kernel, dim3(4096), dim3(256), 0, stream, Wx, Wh, W4, WxB, WhB, W4B);
    hipLaunchKernelGGL(pe1_kernel, dim3(32, 16), dim3(256), 0, stream, wid, emb, pb);
    hipLaunchKernelGGL(pe2_kernel, dim3(32, 16), dim3(256), 0, stream, wid, emb, pb, pe);
    hipLaunchKernelGGL(u3_gemm, dim3(8, 128), dim3(256), 0, stream, wid, emb, W3, u3);
    hipLaunchKernelGGL(bsum_gemm, dim3(8, 128), dim3(256), 0, stream, enc, wid, emb, W1, W2, bsum);

    void* args[] = { (void*)&bias, (void*)&vt1, (void*)&bsum, (void*)&u3, (void*)&pe,
                     (void*)&WxB, (void*)&WhB, (void*)&W4B, (void*)&gxw64, (void*)&gph64,
                     (void*)&sp2, (void*)&state, (void*)&hn0, (void*)&out };
    (void)hipLaunchCooperativeKernel((void*)decode_kernel, dim3(256), dim3(256), args, 0, stream);
}